// Round 3
// baseline (74.747 us; speedup 1.0000x reference)
//
#include <hip/hip_runtime.h>
#include <hip/hip_bf16.h>
#include <math.h>

// ---------------- problem constants ----------------
namespace {
constexpr int BATCH = 4;
constexpr int IMG   = 192;
constexpr int PL    = IMG * IMG;
constexpr int NP1   = 4096;   // 64*64 full-res patches per image
constexpr int N96   = 1024;   // 32*32 patches at 96x96
constexpr int N48   = 256;    // 16*16 patches at 48x48
constexpr int MALL  = 5376;   // 4096 + 1024 + 256 candidate patches
constexpr int RS    = 28;     // fp32 row stride: 27 values + |c|^2 slot
constexpr int NCHUNK = 16;    // m-chunks for argmin partials
constexpr int TPC    = 21;    // 16-wide m-tiles per chunk (16*21*16 = 5376)

// gaussian kernel constants (float32 images of the numpy float32 values)
#define GA 0.27406862f   // gauss1d(1.0) edge
#define GB 0.45186276f   // gauss1d(1.0) center
#define RC 0.33277732f   // gauss1d(10.0) edge
#define RD 0.33444537f   // gauss1d(10.0) center

typedef __bf16 bf16x8 __attribute__((ext_vector_type(8)));
typedef float  f32x4  __attribute__((ext_vector_type(4)));

__device__ __forceinline__ void conv3(const float in[9], const float k[9], float out[9]) {
#pragma unroll
  for (int y = 0; y < 3; ++y)
#pragma unroll
    for (int x = 0; x < 3; ++x) {
      float s = 0.f;
#pragma unroll
      for (int i = 0; i < 3; ++i) {
        int yy = y + i - 1;
        if (yy < 0 || yy > 2) continue;
#pragma unroll
        for (int j = 0; j < 3; ++j) {
          int xx = x + j - 1;
          if (xx < 0 || xx > 2) continue;
          s = fmaf(k[i * 3 + j], in[yy * 3 + xx], s);
        }
      }
      out[y * 3 + x] = s;
    }
}

// gray -> normalized structure-tensor 27-vector + |c|^2 (of the normalized vec)
__device__ __forceinline__ void st_from_gray(const float gray[9], float stv[27], float& cs) {
  const float KX[9] = {GA * GA, 0.f, -GA * GA, GB * GA, 0.f, -GB * GA, GA * GA, 0.f, -GA * GA};
  const float KY[9] = {GA * GA, GA * GB, GA * GA, 0.f, 0.f, 0.f, -GA * GA, -GA * GB, -GA * GA};
  const float KS[9] = {RC * RC, RC * RD, RC * RC, RD * RC, RD * RD, RD * RC, RC * RC, RC * RD, RC * RC};
  float Ix[9], Iy[9];
  conv3(gray, KX, Ix);
  conv3(gray, KY, Iy);
  float Pxx[9], Pyy[9], Pxy[9];
#pragma unroll
  for (int t = 0; t < 9; ++t) {
    Pxx[t] = Ix[t] * Ix[t];
    Pyy[t] = Iy[t] * Iy[t];
    Pxy[t] = Ix[t] * Iy[t];
  }
  conv3(Pxx, KS, stv + 0);
  conv3(Pyy, KS, stv + 9);
  conv3(Pxy, KS, stv + 18);
  float s2 = 0.f;
#pragma unroll
  for (int d = 0; d < 27; ++d) s2 = fmaf(stv[d], stv[d], s2);
  float inv = 1.0f / (sqrtf(s2) + 1e-12f);
  float c = 0.f;
#pragma unroll
  for (int d = 0; d < 27; ++d) {
    stv[d] *= inv;
    c = fmaf(stv[d], stv[d], c);
  }
  cs = c;
}

// ---------------- bicubic taps (jax.image.resize, antialias=False) ----------------
__device__ __forceinline__ void mkw(int k0, int IS, float w[4], int k[4]) {
  const float W4[4] = {-0.0625f, 0.5625f, 0.5625f, -0.0625f};
  float ssum = 0.f;
#pragma unroll
  for (int u = 0; u < 4; ++u) {
    int kk = k0 + u;
    bool v = (kk >= 0) && (kk < IS);
    w[u] = v ? W4[u] : 0.f;
    k[u] = v ? kk : 0;
    ssum += w[u];
  }
  float inv = 1.f / ssum;  // interior: exactly 1.0
#pragma unroll
  for (int u = 0; u < 4; ++u) w[u] *= inv;
}

// resized-grayscale pixel straight from the 3-channel 192x192 image
// (resize and grayscale are both linear -> they commute)
__device__ __forceinline__ float bicubic_gray(const float* __restrict__ im,
                                              int i, int j, int step, int koff) {
  float wr[4], wc[4];
  int kr[4], kc[4];
  mkw(step * i + koff, IMG, wr, kr);
  mkw(step * j + koff, IMG, wc, kc);
  float acc = 0.f;
#pragma unroll
  for (int u = 0; u < 4; ++u) {
    float rs = 0.f;
#pragma unroll
    for (int v = 0; v < 4; ++v) {
      int o = kr[u] * IMG + kc[v];
      float r  = im[o];
      float g2 = im[PL + o];
      float bl = im[2 * PL + o];
      float gy = fmaf(0.114f, bl, fmaf(0.587f, g2, 0.2989f * r));
      rs = fmaf(wc[v], gy, rs);
    }
    acc = fmaf(wr[u], rs, acc);
  }
  return acc;
}

// pack a 28-float row into bf16 hi/lo (32 uints): uints 0..15 hi pairs k=0..31,
// 16..31 lo pairs; k>=28 zero.
__device__ __forceinline__ void pack_row(const float v[28], unsigned* __restrict__ dst) {
  unsigned uh[16], ul[16];
#pragma unroll
  for (int p = 0; p < 16; ++p) {
    float a  = (2 * p < 28) ? v[2 * p] : 0.f;
    float bb = (2 * p + 1 < 28) ? v[2 * p + 1] : 0.f;
    __hip_bfloat16 ah = __float2bfloat16(a);
    __hip_bfloat16 bh = __float2bfloat16(bb);
    float af = __bfloat162float(ah), bf2 = __bfloat162float(bh);
    __hip_bfloat16 al = __float2bfloat16(a - af);
    __hip_bfloat16 bl = __float2bfloat16(bb - bf2);
    uh[p] = ((unsigned)__builtin_bit_cast(unsigned short, bh) << 16) |
            (unsigned)__builtin_bit_cast(unsigned short, ah);
    ul[p] = ((unsigned)__builtin_bit_cast(unsigned short, bl) << 16) |
            (unsigned)__builtin_bit_cast(unsigned short, al);
  }
  uint4* d4 = reinterpret_cast<uint4*>(dst);
  d4[0] = make_uint4(uh[0], uh[1], uh[2], uh[3]);
  d4[1] = make_uint4(uh[4], uh[5], uh[6], uh[7]);
  d4[2] = make_uint4(uh[8], uh[9], uh[10], uh[11]);
  d4[3] = make_uint4(uh[12], uh[13], uh[14], uh[15]);
  d4[4] = make_uint4(ul[0], ul[1], ul[2], ul[3]);
  d4[5] = make_uint4(ul[4], ul[5], ul[6], ul[7]);
  d4[6] = make_uint4(ul[8], ul[9], ul[10], ul[11]);
  d4[7] = make_uint4(ul[12], ul[13], ul[14], ul[15]);
}

__device__ __forceinline__ void store_row28(float* __restrict__ dst, const float v[28]) {
  float4* d4 = reinterpret_cast<float4*>(dst);
#pragma unroll
  for (int i = 0; i < 7; ++i)
    d4[i] = make_float4(v[4 * i], v[4 * i + 1], v[4 * i + 2], v[4 * i + 3]);
}

// ---------------- fused front end: patches + scaled patches + bf16 pack ----------------
// g in [0,16384): main scale (x patch AND gt patch -> p1, p2c, Qp, Cp)
// g in [16384,20480): 96-scale gt patches -> p2c, Cp
// g in [20480,21504): 48-scale gt patches -> p2c, Cp
__global__ void __launch_bounds__(256) prep_kernel(
    const float* __restrict__ x, const float* __restrict__ gt,
    float* __restrict__ p1, float* __restrict__ p2c,
    unsigned* __restrict__ Qp, unsigned* __restrict__ Cp,
    unsigned* __restrict__ ctr) {
  int g = blockIdx.x * 256 + threadIdx.x;
  if (g == 0) ctr[0] = 0;  // reset finalize ticket (stream-ordered before finalize)

  if (g < BATCH * NP1) {
    int b = g >> 12, p = g & (NP1 - 1);
    int hb = p >> 6, wb = p & 63;
    const size_t boff = (size_t)b * 3 * PL + (size_t)(hb * 3) * IMG + wb * 3;

    float gr[9];
    const float* bx = x + boff;
#pragma unroll
    for (int y = 0; y < 3; ++y)
#pragma unroll
      for (int xx = 0; xx < 3; ++xx) {
        int o = y * IMG + xx;
        gr[y * 3 + xx] = fmaf(0.114f, bx[2 * PL + o], fmaf(0.587f, bx[PL + o], 0.2989f * bx[o]));
      }
    float s1[28];
    float cs1;
    st_from_gray(gr, s1, cs1);
    s1[27] = cs1;

    const float* bg = gt + boff;
#pragma unroll
    for (int y = 0; y < 3; ++y)
#pragma unroll
      for (int xx = 0; xx < 3; ++xx) {
        int o = y * IMG + xx;
        gr[y * 3 + xx] = fmaf(0.114f, bg[2 * PL + o], fmaf(0.587f, bg[PL + o], 0.2989f * bg[o]));
      }
    float s2[28];
    float cs2;
    st_from_gray(gr, s2, cs2);
    s2[27] = cs2;

    store_row28(p1 + (size_t)g * RS, s1);
    size_t crow = (size_t)b * MALL + p;
    store_row28(p2c + crow * RS, s2);

    float vc[28];
#pragma unroll
    for (int d = 0; d < 27; ++d) vc[d] = s2[d];
    vc[27] = -cs2;
    pack_row(vc, Cp + crow * 32);

    float vq[28];
#pragma unroll
    for (int d = 0; d < 27; ++d) vq[d] = s1[d] + s2[d];
    vq[27] = 1.0f;
    pack_row(vq, Qp + (size_t)g * 32);
  } else if (g < BATCH * (NP1 + N96)) {
    int q = g - BATCH * NP1;
    int b = q >> 10, p = q & (N96 - 1);
    int hb = p >> 5, wb = p & 31;
    const float* im = gt + (size_t)b * 3 * PL;
    float gr[9];
#pragma unroll
    for (int y = 0; y < 3; ++y)
#pragma unroll
      for (int xx = 0; xx < 3; ++xx)
        gr[y * 3 + xx] = bicubic_gray(im, 3 * hb + y, 3 * wb + xx, 2, -1);
    float s[28];
    float cs;
    st_from_gray(gr, s, cs);
    s[27] = cs;
    size_t crow = (size_t)b * MALL + NP1 + p;
    store_row28(p2c + crow * RS, s);
    float vc[28];
#pragma unroll
    for (int d = 0; d < 27; ++d) vc[d] = s[d];
    vc[27] = -cs;
    pack_row(vc, Cp + crow * 32);
  } else if (g < BATCH * (NP1 + N96 + N48)) {
    int q = g - BATCH * (NP1 + N96);
    int b = q >> 8, p = q & (N48 - 1);
    int hb = p >> 4, wb = p & 15;
    const float* im = gt + (size_t)b * 3 * PL;
    float gr[9];
#pragma unroll
    for (int y = 0; y < 3; ++y)
#pragma unroll
      for (int xx = 0; xx < 3; ++xx)
        gr[y * 3 + xx] = bicubic_gray(im, 3 * hb + y, 3 * wb + xx, 4, 0);
    float s[28];
    float cs;
    st_from_gray(gr, s, cs);
    s[27] = cs;
    size_t crow = (size_t)b * MALL + NP1 + N96 + p;
    store_row28(p2c + crow * RS, s);
    float vc[28];
#pragma unroll
    for (int d = 0; d < 27; ++d) vc[d] = s[d];
    vc[27] = -cs;
    pack_row(vc, Cp + crow * 32);
  }
}

// ---------------- MFMA argmax of t = q.c - |c|^2 over m (bf16x3 split) ----------------
// Wave: 4 n-tiles (64 rows). Grid: (rowgroup=16, chunk=16, batch=4), 256 thr.
// D mapping (16x16x32): col = lane&15 (m within tile), row = (lane>>4)*4 + reg.
__global__ void __launch_bounds__(256, 4) argmin_mfma_kernel(
    const unsigned* __restrict__ Qp, const unsigned* __restrict__ Cp,
    float* __restrict__ pscore, int* __restrict__ pidx) {
  const int lane = threadIdx.x & 63;
  const int w = threadIdx.x >> 6;
  const int chunk = blockIdx.y;
  const int b = blockIdx.z;
  const int nbase = blockIdx.x * 256 + w * 64;
  const int lm = lane & 15, lg = lane >> 4;

  bf16x8 qh[4], ql[4];
#pragma unroll
  for (int t = 0; t < 4; ++t) {
    const unsigned* rp = Qp + ((size_t)(b * NP1 + nbase + t * 16 + lm)) * 32 + lg * 4;
    qh[t] = *reinterpret_cast<const bf16x8*>(rp);
    ql[t] = *reinterpret_cast<const bf16x8*>(rp + 16);
  }

  float best[4][4];
  int idx[4][4];
#pragma unroll
  for (int t = 0; t < 4; ++t)
#pragma unroll
    for (int r = 0; r < 4; ++r) { best[t][r] = -INFINITY; idx[t][r] = 0; }

  const int tile0 = chunk * TPC;
  for (int i = 0; i < TPC; ++i) {
    const int m0 = (tile0 + i) * 16;
    const unsigned* cr = Cp + ((size_t)(b * MALL + m0 + lm)) * 32 + lg * 4;
    bf16x8 ch = *reinterpret_cast<const bf16x8*>(cr);
    bf16x8 cl = *reinterpret_cast<const bf16x8*>(cr + 16);
    const int mi = m0 + lm;
#pragma unroll
    for (int t = 0; t < 4; ++t) {
      f32x4 a = {0.f, 0.f, 0.f, 0.f};
      a = __builtin_amdgcn_mfma_f32_16x16x32_bf16(qh[t], ch, a, 0, 0, 0);
      a = __builtin_amdgcn_mfma_f32_16x16x32_bf16(ql[t], ch, a, 0, 0, 0);
      a = __builtin_amdgcn_mfma_f32_16x16x32_bf16(qh[t], cl, a, 0, 0, 0);
#pragma unroll
      for (int r = 0; r < 4; ++r) {
        bool g = a[r] > best[t][r];
        best[t][r] = g ? a[r] : best[t][r];
        idx[t][r] = g ? mi : idx[t][r];
      }
    }
  }

  // reduce (best, idx) across the 16 lanes of each row-group; min idx on ties
#pragma unroll
  for (int t = 0; t < 4; ++t)
#pragma unroll
    for (int r = 0; r < 4; ++r) {
      float bv = best[t][r];
      int bi = idx[t][r];
#pragma unroll
      for (int mk = 1; mk < 16; mk <<= 1) {
        float ov = __shfl_xor(bv, mk, 64);
        int oi = __shfl_xor(bi, mk, 64);
        bool take = (ov > bv) || (ov == bv && oi < bi);
        bv = take ? ov : bv;
        bi = take ? oi : bi;
      }
      if (lm == 0) {
        int row = nbase + t * 16 + lg * 4 + r;
        size_t o = ((size_t)(b * NP1 + row)) * NCHUNK + chunk;
        pscore[o] = bv;
        pidx[o] = bi;
      }
    }
}

// ---------------- combine partials, gather, L1 partials, ticketed final sum ----------------
__global__ void __launch_bounds__(256) finalize_kernel(
    const float* __restrict__ p1, const float* __restrict__ p2c,
    const float* __restrict__ pscore, const int* __restrict__ pidx,
    float* __restrict__ bsum, unsigned* __restrict__ ctr, float* __restrict__ out) {
  int g = blockIdx.x * 256 + threadIdx.x;  // [0, BATCH*NP1)
  float bt = -INFINITY;
  int bi = 0;
  for (int ms = 0; ms < NCHUNK; ++ms) {
    float s = pscore[(size_t)g * NCHUNK + ms];
    int ix = pidx[(size_t)g * NCHUNK + ms];
    bool gg = (s > bt) || (s == bt && ix < bi);  // ascending m + min-idx tie-break
    bt = gg ? s : bt;
    bi = gg ? ix : bi;
  }
  int b = g >> 12;
  const float* a = p1 + (size_t)g * RS;
  const float* s2 = p2c + ((size_t)b * MALL + bi) * RS;
  float acc = 0.f;
#pragma unroll
  for (int d = 0; d < 27; ++d) acc += fabsf(a[d] - s2[d]);

  __shared__ float red[256];
  red[threadIdx.x] = acc;
  __syncthreads();
  for (int st = 128; st > 0; st >>= 1) {
    if (threadIdx.x < st) red[threadIdx.x] += red[threadIdx.x + st];
    __syncthreads();
  }
  if (threadIdx.x == 0) {
    __hip_atomic_store(&bsum[blockIdx.x], red[0], __ATOMIC_RELEASE, __HIP_MEMORY_SCOPE_AGENT);
    unsigned prev = __hip_atomic_fetch_add(ctr, 1u, __ATOMIC_ACQ_REL, __HIP_MEMORY_SCOPE_AGENT);
    if (prev == 63) {  // last block: deterministic ascending-order sum
      float s = 0.f;
      for (int i = 0; i < 64; ++i)
        s += __hip_atomic_load(&bsum[i], __ATOMIC_ACQUIRE, __HIP_MEMORY_SCOPE_AGENT);
      out[0] = s * (1.0f / 442368.0f);
    }
  }
}

}  // namespace

extern "C" void kernel_launch(void* const* d_in, const int* in_sizes, int n_in,
                              void* d_out, int out_size, void* d_ws, size_t ws_size,
                              hipStream_t stream) {
  const float* x  = (const float*)d_in[0];
  const float* gt = (const float*)d_in[1];
  float* out = (float*)d_out;

  // workspace layout (4-byte slots)
  float* ws = (float*)d_ws;
  float* p1   = ws;                                   // 4*4096*28 = 458752
  float* p2c  = p1 + (size_t)BATCH * NP1 * RS;        // 4*5376*28 = 602112
  unsigned* Qp = (unsigned*)(p2c + (size_t)BATCH * MALL * RS);    // 4*4096*32
  unsigned* Cp = Qp + (size_t)BATCH * NP1 * 32;       // 4*5376*32
  float* pscore = (float*)(Cp + (size_t)BATCH * MALL * 32);       // 4*4096*16
  int*   pidx   = (int*)(pscore + (size_t)BATCH * NP1 * NCHUNK);  // 4*4096*16
  float* bsum   = (float*)(pidx + (size_t)BATCH * NP1 * NCHUNK);  // 64
  unsigned* ctr = (unsigned*)(bsum + 64);                         // 1

  // fused front end: 84 blocks cover main + 96-scale + 48-scale patches
  {
    int tot = BATCH * (NP1 + N96 + N48);  // 21504
    prep_kernel<<<tot / 256, 256, 0, stream>>>(x, gt, p1, p2c, Qp, Cp, ctr);
  }

  // MFMA chunked argmax
  {
    dim3 grid(16, NCHUNK, BATCH);
    argmin_mfma_kernel<<<grid, 256, 0, stream>>>(Qp, Cp, pscore, pidx);
  }

  // finalize: combine chunks + L1 loss + ticketed deterministic final sum
  finalize_kernel<<<(BATCH * NP1) / 256, 256, 0, stream>>>(p1, p2c, pscore, pidx, bsum, ctr, out);
}